// Round 3
// baseline (108.783 us; speedup 1.0000x reference)
//
#include <hip/hip_runtime.h>
#include <hip/hip_cooperative_groups.h>
#include <math.h>

namespace cg = cooperative_groups;

// B=8, PN=8 -> BP=64; PL=511 -> L=512; NV=2; H=8; DK=DV=32; D=256; DM=512; HID=1024.
constexpr int L   = 512;
constexpr int D   = 256;
constexpr int DM  = 512;
constexpr int HID = 1024;
constexpr float INV_SQRT_DK = 0.17677669529663687f;  // 1/sqrt(32)
constexpr float LN1000_D16  = 0.4317347049836665f;   // ln(1000)/16

// One cooperative kernel, 4 phases, 3 grid syncs.
// Grid: 256 blocks x 512 threads (1 block/CU -> co-residency guaranteed).
__global__ __launch_bounds__(512, 1)
void k_all(const float* __restrict__ x, const float* __restrict__ t,
           const int* __restrict__ mask, const float* __restrict__ emb,
           const float* __restrict__ Wq, const float* __restrict__ Wk,
           const float* __restrict__ Wv, const float* __restrict__ Wo,
           const float* __restrict__ ln_g, const float* __restrict__ ln_b,
           const float* __restrict__ W1, const float* __restrict__ b1,
           const float* __restrict__ W2, const float* __restrict__ b2,
           float* __restrict__ out,
           float* __restrict__ last, float* __restrict__ hid,
           float* __restrict__ partial) {
  cg::grid_group grid = cg::this_grid();
  const int bid  = blockIdx.x;
  const int tid  = threadIdx.x;
  const int lane = tid & 63;
  const int wid  = tid >> 6;

  __shared__ float s_xx0[L], s_xx1[L];
  __shared__ float s_w[2][6][32];      // per-head {wq0,wq1,wk0,wk1,wv0,wv1}
  __shared__ float s_q[32];
  __shared__ float s_red[24];
  __shared__ int   s_m0;
  __shared__ float s_a[4][257];        // P1 last tile
  __shared__ float s_ps[4][64];        // P1 K-split combine
  __shared__ float s_hs[64][33];       // P2 hid tile
  __shared__ float s_w2[32][32];       // P2 W2 tile
  __shared__ float s_yp[2][256];       // P3 partial-reduce combine
  __shared__ float s_yn[256];          // P3 layernorm output
  __shared__ float s_op[4][128];       // P3 out K-split combine

  // ============ P0: attention (2 (bp,head) units per block) ============
  {
    const int bp = bid >> 2;
    const int hbase = (bid & 3) * 2;
    if (tid == 0) { s_xx0[0] = emb[0]; s_xx1[0] = emb[1]; s_m0 = mask[bp * L]; }
    else {
      float2 v = reinterpret_cast<const float2*>(x)[bp * (L - 1) + tid - 1];
      s_xx0[tid] = v.x; s_xx1[tid] = v.y;
    }
    if (tid < 384) {
      const int hh = tid / 192, rem = tid % 192, r = rem >> 5, c = rem & 31;
      const int h = hbase + hh;
      const float* src;
      switch (r) {
        case 0:  src = Wq + h * 32;        break;
        case 1:  src = Wq + 256 + h * 32;  break;
        case 2:  src = Wk + h * 32;        break;
        case 3:  src = Wk + 256 + h * 32;  break;
        case 4:  src = Wv + h * 32;        break;
        default: src = Wv + 256 + h * 32;  break;
      }
      s_w[hh][r][c] = src[c];
    }
    const float tl = t[bp * L + tid];
    const int   ml = mask[bp * L + tid];
    float cj[16], sj[16];
    #pragma unroll
    for (int j = 0; j < 16; ++j) {
      const float theta = expf(-(float)j * LN1000_D16);  // folds to literal
      sincosf(tl * theta, &sj[j], &cj[j]);
    }
    __syncthreads();
    const float xl0 = s_xx0[tid], xl1 = s_xx1[tid];
    const bool masked = (s_m0 * ml) == 0;
    const float t0 = t[bp * L];
    #pragma unroll
    for (int hh = 0; hh < 2; ++hh) {
      if (tid < 16) {  // RoPE'd, pre-scaled query row for this head
        const float re = s_xx0[0] * s_w[hh][0][2*tid]     + s_xx1[0] * s_w[hh][1][2*tid];
        const float im = s_xx0[0] * s_w[hh][0][2*tid + 1] + s_xx1[0] * s_w[hh][1][2*tid + 1];
        float s0, c0;
        sincosf(t0 * expf(-(float)tid * LN1000_D16), &s0, &c0);
        s_q[2*tid]     = (re * c0 - im * s0) * INV_SQRT_DK;
        s_q[2*tid + 1] = (re * s0 + im * c0) * INV_SQRT_DK;
      }
      __syncthreads();
      float sc = 0.f;
      #pragma unroll
      for (int j = 0; j < 16; ++j) {
        const int c = 2 * j;
        const float xr  = xl0 * s_w[hh][2][c]     + xl1 * s_w[hh][3][c];
        const float xi  = xl0 * s_w[hh][2][c + 1] + xl1 * s_w[hh][3][c + 1];
        const float kre = xr * cj[j] - xi * sj[j];
        const float kim = xr * sj[j] + xi * cj[j];
        sc += s_q[c] * kre + s_q[c + 1] * kim;
      }
      if (masked) sc = -1e9f;
      float mx = sc;
      #pragma unroll
      for (int o = 32; o; o >>= 1) mx = fmaxf(mx, __shfl_xor(mx, o));
      if (lane == 0) s_red[wid] = mx;
      __syncthreads();
      mx = s_red[0];
      #pragma unroll
      for (int w = 1; w < 8; ++w) mx = fmaxf(mx, s_red[w]);
      const float e = expf(sc - mx);
      float se = e, s0a = e * xl0, s1a = e * xl1;
      #pragma unroll
      for (int o = 32; o; o >>= 1) {
        se  += __shfl_xor(se, o);
        s0a += __shfl_xor(s0a, o);
        s1a += __shfl_xor(s1a, o);
      }
      __syncthreads();
      if (lane == 0) { s_red[wid] = se; s_red[8 + wid] = s0a; s_red[16 + wid] = s1a; }
      __syncthreads();
      se = 0.f; s0a = 0.f; s1a = 0.f;
      #pragma unroll
      for (int w = 0; w < 8; ++w) { se += s_red[w]; s0a += s_red[8 + w]; s1a += s_red[16 + w]; }
      if (tid < 32) {  // attn@V == ((attn@xx)@Wv), NV=2, V has no RoPE
        const int h = hbase + hh;
        last[bp * 256 + h * 32 + tid] = (s0a * s_w[hh][4][tid] + s1a * s_w[hh][5][tid]) / se;
      }
      __syncthreads();
    }
  }
  grid.sync();

  // ============ P1: hid = relu(last @ W1 + b1) ============
  // 256 blocks = 16 ntiles(64 cols) x 16 mtiles(4 rows); 2-way K-split/thread.
  {
    const int nt = bid & 15, mt = bid >> 4;
    const int rbase = mt * 4, cbase = nt * 64;
    #pragma unroll
    for (int q = 0; q < 2; ++q) {
      const int idx = tid + q * 512;
      s_a[idx >> 8][idx & 255] = last[(rbase + (idx >> 8)) * 256 + (idx & 255)];
    }
    __syncthreads();
    const int j = tid & 63, r = (tid >> 6) & 3, kh = tid >> 8;
    const int jg = cbase + j;
    float acc = 0.f;
    #pragma unroll 8
    for (int k = kh * 128; k < kh * 128 + 128; ++k)
      acc = fmaf(s_a[r][k], W1[k * HID + jg], acc);
    if (kh == 1) s_ps[r][j] = acc;
    __syncthreads();
    if (kh == 0)
      hid[(rbase + r) * HID + jg] = fmaxf(acc + s_ps[r][j] + b1[jg], 0.f);
  }
  grid.sync();

  // ============ P2: partial[kt] = hid[:, kslice32] @ W2[kslice32, ntile32] ============
  // 256 blocks = 32 ktiles x 8 ntiles.
  {
    const int kt = bid >> 3, nt = bid & 7;
    const int kbase = kt * 32, cbase = nt * 32;
    #pragma unroll
    for (int q = 0; q < 4; ++q) {
      const int idx = tid + q * 512;
      s_hs[idx >> 5][idx & 31] = hid[(idx >> 5) * HID + kbase + (idx & 31)];
    }
    #pragma unroll
    for (int q = 0; q < 2; ++q) {
      const int idx = tid + q * 512;
      s_w2[idx >> 5][idx & 31] = W2[(kbase + (idx >> 5)) * D + cbase + (idx & 31)];
    }
    __syncthreads();
    const int col = tid & 31, rg = tid >> 5;  // rg 0..15 -> rows 4rg..4rg+3
    float a0 = 0.f, a1 = 0.f, a2 = 0.f, a3 = 0.f;
    #pragma unroll
    for (int k = 0; k < 32; ++k) {
      const float w = s_w2[k][col];
      a0 = fmaf(s_hs[4*rg + 0][k], w, a0);
      a1 = fmaf(s_hs[4*rg + 1][k], w, a1);
      a2 = fmaf(s_hs[4*rg + 2][k], w, a2);
      a3 = fmaf(s_hs[4*rg + 3][k], w, a3);
    }
    partial[(kt * 64 + 4*rg + 0) * 256 + cbase + col] = a0;
    partial[(kt * 64 + 4*rg + 1) * 256 + cbase + col] = a1;
    partial[(kt * 64 + 4*rg + 2) * 256 + cbase + col] = a2;
    partial[(kt * 64 + 4*rg + 3) * 256 + cbase + col] = a3;
  }
  grid.sync();

  // ============ P3: y = last + b2 + sum(partial); LN; out tile = yn @ Wo ============
  // 256 blocks = 64 bp x 4 out-quarters(128 cols). LN redundant x4 (cheap).
  {
    const int bp = bid >> 2, ot = bid & 3;
    {
      const int c = tid & 255, kh = tid >> 8;
      float acc = 0.f;
      #pragma unroll
      for (int kt = kh * 16; kt < kh * 16 + 16; ++kt)
        acc += partial[(kt * 64 + bp) * 256 + c];
      s_yp[kh][c] = acc;
    }
    __syncthreads();
    float y = 0.f;
    if (tid < 256) y = last[bp * 256 + tid] + b2[tid] + s_yp[0][tid] + s_yp[1][tid];
    float ssum = (tid < 256) ? y : 0.f, ssq = (tid < 256) ? y * y : 0.f;
    #pragma unroll
    for (int o = 32; o; o >>= 1) { ssum += __shfl_xor(ssum, o); ssq += __shfl_xor(ssq, o); }
    if (tid < 256 && lane == 0) { s_red[wid] = ssum; s_red[8 + wid] = ssq; }
    __syncthreads();
    ssum = s_red[0] + s_red[1] + s_red[2] + s_red[3];
    ssq  = s_red[8] + s_red[9] + s_red[10] + s_red[11];
    const float mu   = ssum / 256.f;
    const float var  = ssq / 256.f - mu * mu;
    const float rstd = rsqrtf(var + 1e-5f);
    if (tid < 256) s_yn[tid] = (y - mu) * rstd * ln_g[tid] + ln_b[tid];
    __syncthreads();
    const int col = ot * 128 + (tid & 127), kq = tid >> 7;
    float acc = 0.f;
    #pragma unroll 8
    for (int i = kq * 64; i < kq * 64 + 64; ++i)
      acc = fmaf(s_yn[i], Wo[i * DM + col], acc);
    s_op[kq][tid & 127] = acc;
    __syncthreads();
    if (tid < 128)
      out[bp * DM + ot * 128 + tid] =
          s_op[0][tid] + s_op[1][tid] + s_op[2][tid] + s_op[3][tid];
  }
}

extern "C" void kernel_launch(void* const* d_in, const int* in_sizes, int n_in,
                              void* d_out, int out_size, void* d_ws, size_t ws_size,
                              hipStream_t stream) {
  const float* x    = (const float*)d_in[0];
  const float* t    = (const float*)d_in[1];
  const int*   mask = (const int*)  d_in[2];
  const float* emb  = (const float*)d_in[3];
  const float* Wq   = (const float*)d_in[4];
  const float* Wk   = (const float*)d_in[5];
  const float* Wv   = (const float*)d_in[6];
  const float* Wo   = (const float*)d_in[7];
  const float* lng  = (const float*)d_in[8];
  const float* lnb  = (const float*)d_in[9];
  const float* W1   = (const float*)d_in[10];
  const float* b1   = (const float*)d_in[11];
  const float* W2   = (const float*)d_in[12];
  const float* b2   = (const float*)d_in[13];
  float* out = (float*)d_out;

  float* ws      = (float*)d_ws;
  float* last    = ws;                     // 64*256
  float* hid     = ws + 16384;             // 64*1024
  float* partial = ws + 16384 + 65536;     // 32*64*256

  void* args[] = {&x, &t, &mask, &emb, &Wq, &Wk, &Wv, &Wo, &lng, &lnb,
                  &W1, &b1, &W2, &b2, &out, &last, &hid, &partial};
  hipLaunchCooperativeKernel((const void*)k_all, dim3(256), dim3(512),
                             args, 0, stream);
}

// Round 4
// 93.685 us; speedup vs baseline: 1.1612x; 1.1612x over previous
//
#include <hip/hip_runtime.h>
#include <math.h>

// B=8, PN=8 -> BP=64; PL=511 -> L=512; NV=2; H=8; DK=DV=32; D=256; DM=512; HID=1024.
namespace {
constexpr int L   = 512;
constexpr int D   = 256;
constexpr int DM  = 512;
constexpr int HID = 1024;
constexpr float INV_SQRT_DK = 0.17677669529663687f;  // 1/sqrt(32)

// thetas[j] = 1000^(-j/16), precomputed literals (guaranteed no libm at runtime)
__device__ __constant__ float THETA[16] = {
  1.0f,           0.64938163f,  0.42169650f,  0.27384196f,
  0.17782794f,    0.11547820f,  0.074989421f, 0.048696753f,
  0.031622777f,   0.020535250f, 0.013335214f, 0.0086596432f,
  0.0056234133f,  0.0036517412f,0.0023713737f,0.0015399265f };

// ---------------- K1: attention, one block per (bp, head) ----------------
__global__ __launch_bounds__(512, 2)
void k_attn(const float* __restrict__ x, const float* __restrict__ t,
            const int* __restrict__ mask, const float* __restrict__ emb,
            const float* __restrict__ Wq, const float* __restrict__ Wk,
            const float* __restrict__ Wv, float* __restrict__ last) {
  const int bp = blockIdx.x >> 3, h = blockIdx.x & 7;
  const int tid = threadIdx.x, lane = tid & 63, wid = tid >> 6;

  __shared__ float xx0s[L], xx1s[L];
  __shared__ float wq0[32], wq1[32], wk0[32], wk1[32], wv0[32], wv1[32];
  __shared__ float qh[32];
  __shared__ float red[24];
  __shared__ int   m0s;

  if (tid == 0) { xx0s[0] = emb[0]; xx1s[0] = emb[1]; m0s = mask[bp * L]; }
  else {
    float2 v = reinterpret_cast<const float2*>(x)[bp * (L - 1) + tid - 1];
    xx0s[tid] = v.x; xx1s[tid] = v.y;
  }
  if (tid < 32) {
    wq0[tid] = Wq[h * 32 + tid];       wq1[tid] = Wq[256 + h * 32 + tid];
    wk0[tid] = Wk[h * 32 + tid];       wk1[tid] = Wk[256 + h * 32 + tid];
    wv0[tid] = Wv[h * 32 + tid];       wv1[tid] = Wv[256 + h * 32 + tid];
  }

  // per-thread RoPE table for key position l = tid (hardware sin/cos)
  const float tl = t[bp * L + tid];
  const int   ml = mask[bp * L + tid];
  float cj[16], sj[16];
  #pragma unroll
  for (int j = 0; j < 16; ++j) __sincosf(tl * THETA[j], &sj[j], &cj[j]);
  __syncthreads();

  if (tid < 16) {  // query row (pos 0) for this head, RoPE'd + pre-scaled
    const float t0 = t[bp * L];
    const float re = xx0s[0] * wq0[2 * tid]     + xx1s[0] * wq1[2 * tid];
    const float im = xx0s[0] * wq0[2 * tid + 1] + xx1s[0] * wq1[2 * tid + 1];
    float s0, c0;
    __sincosf(t0 * THETA[tid], &s0, &c0);
    qh[2 * tid]     = (re * c0 - im * s0) * INV_SQRT_DK;
    qh[2 * tid + 1] = (re * s0 + im * c0) * INV_SQRT_DK;
  }
  __syncthreads();

  const float xl0 = xx0s[tid], xl1 = xx1s[tid];
  float sc = 0.f;
  #pragma unroll
  for (int j = 0; j < 16; ++j) {
    const int c = 2 * j;
    const float xr  = xl0 * wk0[c]     + xl1 * wk1[c];
    const float xi  = xl0 * wk0[c + 1] + xl1 * wk1[c + 1];
    const float kre = xr * cj[j] - xi * sj[j];
    const float kim = xr * sj[j] + xi * cj[j];
    sc += qh[c] * kre + qh[c + 1] * kim;
  }
  if ((m0s * ml) == 0) sc = -1e9f;

  // block max over 512
  float mx = sc;
  #pragma unroll
  for (int o = 32; o; o >>= 1) mx = fmaxf(mx, __shfl_xor(mx, o));
  if (lane == 0) red[wid] = mx;
  __syncthreads();
  mx = red[0];
  #pragma unroll
  for (int w = 1; w < 8; ++w) mx = fmaxf(mx, red[w]);

  // exp + fused triple reduction: sum(e), sum(e*xx0), sum(e*xx1)
  const float e = expf(sc - mx);
  float se = e, s0a = e * xl0, s1a = e * xl1;
  #pragma unroll
  for (int o = 32; o; o >>= 1) {
    se  += __shfl_xor(se, o);
    s0a += __shfl_xor(s0a, o);
    s1a += __shfl_xor(s1a, o);
  }
  __syncthreads();
  if (lane == 0) { red[wid] = se; red[8 + wid] = s0a; red[16 + wid] = s1a; }
  __syncthreads();
  se = 0.f; s0a = 0.f; s1a = 0.f;
  #pragma unroll
  for (int w = 0; w < 8; ++w) { se += red[w]; s0a += red[8 + w]; s1a += red[16 + w]; }

  // attn@V == ((attn@xx)@Wv): NV=2, V carries no RoPE
  if (tid < 32) last[bp * 256 + h * 32 + tid] = (s0a * wv0[tid] + s1a * wv1[tid]) / se;
}

// ---------------- K2: fused FFN1+FFN2 K-partial ----------------
// 256 blocks = 16 kt x 16 mt; 256 threads (wave r owns bp-row mt*4+r).
// hid tile [4][64] = relu(last_tile @ W1[:,kslice] + b1); then
// partial[kt][4 rows][256] = hid_tile @ W2[kslice,:].
__global__ __launch_bounds__(256, 4)
void k_ffn(const float* __restrict__ last, const float* __restrict__ W1,
           const float* __restrict__ b1, const float* __restrict__ W2,
           float* __restrict__ partial) {
  const int mt = blockIdx.x & 15, kt = blockIdx.x >> 4;
  const int tid = threadIdx.x, lane = tid & 63, r = tid >> 6;  // r = wave = row

  __shared__ float ls[4][256];
  __shared__ float hs[4][64];

  // wave r stages its own row of `last` (float4, coalesced, 1KB/wave)
  {
    float4 v = reinterpret_cast<const float4*>(last + (mt * 4 + r) * 256)[lane];
    *reinterpret_cast<float4*>(&ls[r][lane * 4]) = v;
  }
  __syncthreads();

  // hid[r][k] for k = lane
  const int kg = kt * 64 + lane;
  float acc = b1[kg];
  #pragma unroll 8
  for (int i = 0; i < 256; ++i) acc = fmaf(ls[r][i], W1[i * HID + kg], acc);
  hs[r][lane] = fmaxf(acc, 0.f);
  __syncthreads();

  // partial contribution: row r, cols q*64+lane, sum over this k-slice
  const int prow = (kt * 64 + mt * 4 + r) * 256;
  #pragma unroll
  for (int q = 0; q < 4; ++q) {
    const int c = q * 64 + lane;
    float a = 0.f;
    #pragma unroll
    for (int k = 0; k < 64; ++k)
      a = fmaf(hs[r][k], W2[(kt * 64 + k) * D + c], a);
    partial[prow + c] = a;
  }
}

// ---------------- K3: reduce partials + residual + LN + out tile ----------------
// 256 blocks = 64 bp x 4 col-quarters(128); 256 threads. LN redundant x4 (cheap).
__global__ __launch_bounds__(256, 4)
void k_tail(const float* __restrict__ last, const float* __restrict__ partial,
            const float* __restrict__ b2, const float* __restrict__ ln_g,
            const float* __restrict__ ln_b, const float* __restrict__ Wo,
            float* __restrict__ out) {
  const int bp = blockIdx.x >> 2, ct = blockIdx.x & 3;
  const int tid = threadIdx.x, lane = tid & 63, wid = tid >> 6;

  __shared__ float red[8];
  __shared__ float s_yn[256];
  __shared__ float s_op[2][128];

  // y = last + b2 + sum_kt partial
  float y = last[bp * 256 + tid] + b2[tid];
  #pragma unroll
  for (int kt = 0; kt < 16; ++kt) y += partial[(kt * 64 + bp) * 256 + tid];

  // layernorm stats over 256 (4 waves)
  float ssum = y, ssq = y * y;
  #pragma unroll
  for (int o = 32; o; o >>= 1) { ssum += __shfl_xor(ssum, o); ssq += __shfl_xor(ssq, o); }
  if (lane == 0) { red[wid] = ssum; red[4 + wid] = ssq; }
  __syncthreads();
  ssum = red[0] + red[1] + red[2] + red[3];
  ssq  = red[4] + red[5] + red[6] + red[7];
  const float mu   = ssum / 256.f;
  const float var  = ssq / 256.f - mu * mu;
  const float rstd = rsqrtf(var + 1e-5f);
  s_yn[tid] = (y - mu) * rstd * ln_g[tid] + ln_b[tid];
  __syncthreads();

  // out tile: 128 cols, K split in 2 halves across threads
  const int col = ct * 128 + (tid & 127), kh = tid >> 7;
  float a = 0.f;
  #pragma unroll 8
  for (int i = kh * 128; i < kh * 128 + 128; ++i)
    a = fmaf(s_yn[i], Wo[i * DM + col], a);
  s_op[kh][tid & 127] = a;
  __syncthreads();
  if (tid < 128) out[bp * DM + ct * 128 + tid] = s_op[0][tid] + s_op[1][tid];
}
}  // namespace

extern "C" void kernel_launch(void* const* d_in, const int* in_sizes, int n_in,
                              void* d_out, int out_size, void* d_ws, size_t ws_size,
                              hipStream_t stream) {
  const float* x    = (const float*)d_in[0];
  const float* t    = (const float*)d_in[1];
  const int*   mask = (const int*)  d_in[2];
  const float* emb  = (const float*)d_in[3];
  const float* Wq   = (const float*)d_in[4];
  const float* Wk   = (const float*)d_in[5];
  const float* Wv   = (const float*)d_in[6];
  const float* Wo   = (const float*)d_in[7];
  const float* lng  = (const float*)d_in[8];
  const float* lnb  = (const float*)d_in[9];
  const float* W1   = (const float*)d_in[10];
  const float* b1   = (const float*)d_in[11];
  const float* W2   = (const float*)d_in[12];
  const float* b2   = (const float*)d_in[13];
  float* out = (float*)d_out;

  float* ws      = (float*)d_ws;
  float* last    = ws;            // 64*256
  float* partial = ws + 16384;    // 16*64*256

  k_attn<<<512, 512, 0, stream>>>(x, t, mask, emb, Wq, Wk, Wv, last);
  k_ffn <<<256, 256, 0, stream>>>(last, W1, b1, W2, partial);
  k_tail<<<256, 256, 0, stream>>>(last, partial, b2, lng, lnb, Wo, out);
}

// Round 5
// 23.331 us; speedup vs baseline: 4.6627x; 4.0156x over previous
//
#include <hip/hip_runtime.h>
#include <math.h>

// B=8, PN=8 -> BP=64; PL=511 -> L=512; NV=2; H=8; DK=DV=32; D=256; DM=512; HID=1024.
namespace {
constexpr int L   = 512;
constexpr int D   = 256;
constexpr int DM  = 512;
constexpr int HID = 1024;
constexpr float INV_SQRT_DK = 0.17677669529663687f;  // 1/sqrt(32)

// thetas[j] = 1000^(-j/16), precomputed literals
__device__ __constant__ float THETA[16] = {
  1.0f,           0.64938163f,  0.42169650f,  0.27384196f,
  0.17782794f,    0.11547820f,  0.074989421f, 0.048696753f,
  0.031622777f,   0.020535250f, 0.013335214f, 0.0086596432f,
  0.0056234133f,  0.0036517412f,0.0023713737f,0.0015399265f };

// ---------------- K1: attention, one block per (bp, head) ----------------
// bp = bid & 63 so a patch's 8 head-blocks co-locate on one XCD (xx L2 reuse).
__global__ __launch_bounds__(512, 2)
void k_attn(const float* __restrict__ x, const float* __restrict__ t,
            const int* __restrict__ mask, const float* __restrict__ emb,
            const float* __restrict__ Wq, const float* __restrict__ Wk,
            const float* __restrict__ Wv, float* __restrict__ last) {
  const int bp = blockIdx.x & 63, h = blockIdx.x >> 6;
  const int tid = threadIdx.x, lane = tid & 63, wid = tid >> 6;

  __shared__ float xx0s[L], xx1s[L];
  __shared__ float wq0[32], wq1[32], wk0[32], wk1[32], wv0[32], wv1[32];
  __shared__ float qh[32];
  __shared__ float red[24];
  __shared__ int   m0s;

  if (tid == 0) { xx0s[0] = emb[0]; xx1s[0] = emb[1]; m0s = mask[bp * L]; }
  else {
    float2 v = reinterpret_cast<const float2*>(x)[bp * (L - 1) + tid - 1];
    xx0s[tid] = v.x; xx1s[tid] = v.y;
  }
  if (tid < 32) {
    wq0[tid] = Wq[h * 32 + tid];       wq1[tid] = Wq[256 + h * 32 + tid];
    wk0[tid] = Wk[h * 32 + tid];       wk1[tid] = Wk[256 + h * 32 + tid];
    wv0[tid] = Wv[h * 32 + tid];       wv1[tid] = Wv[256 + h * 32 + tid];
  }

  const float tl = t[bp * L + tid];
  const int   ml = mask[bp * L + tid];
  float cj[16], sj[16];
  #pragma unroll
  for (int j = 0; j < 16; ++j) __sincosf(tl * THETA[j], &sj[j], &cj[j]);
  __syncthreads();

  if (tid < 16) {  // query row (pos 0), RoPE'd + pre-scaled
    const float t0 = t[bp * L];
    const float re = xx0s[0] * wq0[2 * tid]     + xx1s[0] * wq1[2 * tid];
    const float im = xx0s[0] * wq0[2 * tid + 1] + xx1s[0] * wq1[2 * tid + 1];
    float s0, c0;
    __sincosf(t0 * THETA[tid], &s0, &c0);
    qh[2 * tid]     = (re * c0 - im * s0) * INV_SQRT_DK;
    qh[2 * tid + 1] = (re * s0 + im * c0) * INV_SQRT_DK;
  }
  __syncthreads();

  const float xl0 = xx0s[tid], xl1 = xx1s[tid];
  float sc = 0.f;
  #pragma unroll
  for (int j = 0; j < 16; ++j) {
    const int c = 2 * j;
    const float xr  = xl0 * wk0[c]     + xl1 * wk1[c];
    const float xi  = xl0 * wk0[c + 1] + xl1 * wk1[c + 1];
    const float kre = xr * cj[j] - xi * sj[j];
    const float kim = xr * sj[j] + xi * cj[j];
    sc += qh[c] * kre + qh[c + 1] * kim;
  }
  if ((m0s * ml) == 0) sc = -1e9f;

  float mx = sc;
  #pragma unroll
  for (int o = 32; o; o >>= 1) mx = fmaxf(mx, __shfl_xor(mx, o));
  if (lane == 0) red[wid] = mx;
  __syncthreads();
  mx = red[0];
  #pragma unroll
  for (int w = 1; w < 8; ++w) mx = fmaxf(mx, red[w]);

  const float e = expf(sc - mx);
  float se = e, s0a = e * xl0, s1a = e * xl1;
  #pragma unroll
  for (int o = 32; o; o >>= 1) {
    se  += __shfl_xor(se, o);
    s0a += __shfl_xor(s0a, o);
    s1a += __shfl_xor(s1a, o);
  }
  __syncthreads();
  if (lane == 0) { red[wid] = se; red[8 + wid] = s0a; red[16 + wid] = s1a; }
  __syncthreads();
  se = 0.f; s0a = 0.f; s1a = 0.f;
  #pragma unroll
  for (int w = 0; w < 8; ++w) { se += red[w]; s0a += red[8 + w]; s1a += red[16 + w]; }

  // attn@V == ((attn@xx)@Wv): NV=2, V carries no RoPE
  if (tid < 32) last[bp * 256 + h * 32 + tid] = (s0a * wv0[tid] + s1a * wv1[tid]) / se;
}

// ---------------- K2: fused FFN1+FFN2, MLP-optimized ----------------
// grid 256: kt = bid&15 (same-kt blocks share an XCD), mt = bid>>4 (4 bp rows).
// 512 threads = 8 waves: wave w -> r = w&3 (row), kh = w>>2 (K-half of 256).
__global__ __launch_bounds__(512, 2)
void k_ffn(const float* __restrict__ last, const float* __restrict__ W1,
           const float* __restrict__ b1, const float* __restrict__ W2,
           float* __restrict__ partial) {
  const int kt = blockIdx.x & 15, mt = blockIdx.x >> 4;
  const int tid = threadIdx.x, lane = tid & 63;
  const int wave = tid >> 6, r = wave & 3, kh = wave >> 2;

  __shared__ float ls[4][256];
  __shared__ float s_part[2][4][64];
  __shared__ float hs[4][64];

  // stage `last` tile (4 rows x 256), coalesced
  #pragma unroll
  for (int q = 0; q < 2; ++q) {
    const int idx = tid + q * 512;
    ls[idx >> 8][idx & 255] = last[(mt * 4 + (idx >> 8)) * 256 + (idx & 255)];
  }
  __syncthreads();

  // W1 phase: col j = kt*64+lane, K-half kh, 4 interleaved acc chains.
  const int j = kt * 64 + lane;
  {
    const float* w1p = W1 + (size_t)(kh * 128) * HID + j;
    const float* lp  = &ls[r][kh * 128];
    float a0 = 0.f, a1 = 0.f, a2 = 0.f, a3 = 0.f;
    #pragma unroll 8
    for (int ii = 0; ii < 32; ++ii) {
      const float w_0 = w1p[(4 * ii + 0) * HID];
      const float w_1 = w1p[(4 * ii + 1) * HID];
      const float w_2 = w1p[(4 * ii + 2) * HID];
      const float w_3 = w1p[(4 * ii + 3) * HID];
      a0 = fmaf(lp[4 * ii + 0], w_0, a0);
      a1 = fmaf(lp[4 * ii + 1], w_1, a1);
      a2 = fmaf(lp[4 * ii + 2], w_2, a2);
      a3 = fmaf(lp[4 * ii + 3], w_3, a3);
    }
    s_part[kh][r][lane] = (a0 + a1) + (a2 + a3);
  }
  __syncthreads();
  if (kh == 0)
    hs[r][lane] = fmaxf(s_part[0][r][lane] + s_part[1][r][lane] + b1[j], 0.f);
  __syncthreads();

  // W2 phase: row r, col pair c0 = ch*128 + 2*lane (+1); float2 loads, 2 chains.
  {
    const int ch = kh;
    const int c0 = ch * 128 + 2 * lane;
    const float* w2p = W2 + (size_t)(kt * 64) * D + c0;
    float f0 = 0.f, f1 = 0.f;
    #pragma unroll 16
    for (int k = 0; k < 64; ++k) {
      const float2 w = *reinterpret_cast<const float2*>(w2p + (size_t)k * D);
      const float hv = hs[r][k];
      f0 = fmaf(hv, w.x, f0);
      f1 = fmaf(hv, w.y, f1);
    }
    float2 o = make_float2(f0, f1);
    *reinterpret_cast<float2*>(&partial[(size_t)(kt * 64 + mt * 4 + r) * 256 + c0]) = o;
  }
}

// ---------------- K3: reduce partials + residual + LN + out tile ----------------
// grid 256: ct = bid&3 (same Wo quarter per XCD), bp = bid>>2; 512 threads.
__global__ __launch_bounds__(512, 2)
void k_tail(const float* __restrict__ last, const float* __restrict__ partial,
            const float* __restrict__ b2, const float* __restrict__ ln_g,
            const float* __restrict__ ln_b, const float* __restrict__ Wo,
            float* __restrict__ out) {
  const int ct = blockIdx.x & 3, bp = blockIdx.x >> 2;
  const int tid = threadIdx.x, lane = tid & 63, wid = tid >> 6;

  __shared__ float s_y[2][256];
  __shared__ float s_yn[256];
  __shared__ float s_op[8][128];
  __shared__ float red[8];

  // Phase A: partial reduce, 2-way split over kt (8 independent loads each)
  {
    const int col = tid & 255, khh = tid >> 8;
    float acc = khh ? 0.f : (last[bp * 256 + col] + b2[col]);
    #pragma unroll
    for (int kt = khh * 8; kt < khh * 8 + 8; ++kt)
      acc += partial[(size_t)(kt * 64 + bp) * 256 + col];
    s_y[khh][col] = acc;
  }
  __syncthreads();

  // Phase B: layernorm over 256 (waves 0-3 active for stats)
  float y = 0.f;
  if (tid < 256) y = s_y[0][tid] + s_y[1][tid];
  float ssum = (tid < 256) ? y : 0.f, ssq = (tid < 256) ? y * y : 0.f;
  #pragma unroll
  for (int o = 32; o; o >>= 1) { ssum += __shfl_xor(ssum, o); ssq += __shfl_xor(ssq, o); }
  if (tid < 256 && lane == 0) { red[wid] = ssum; red[4 + wid] = ssq; }
  __syncthreads();
  ssum = red[0] + red[1] + red[2] + red[3];
  ssq  = red[4] + red[5] + red[6] + red[7];
  const float mu   = ssum / 256.f;
  const float var  = ssq / 256.f - mu * mu;
  const float rstd = rsqrtf(var + 1e-5f);
  if (tid < 256) s_yn[tid] = (y - mu) * rstd * ln_g[tid] + ln_b[tid];
  __syncthreads();

  // Phase C: out tile (128 cols), float2 Wo loads, 8-way K-split
  {
    const int l6 = tid & 63, kq = tid >> 6;        // kq in [0,8)
    const int c0 = ct * 128 + 2 * l6;
    float f0 = 0.f, f1 = 0.f;
    #pragma unroll 8
    for (int i = kq * 32; i < kq * 32 + 32; ++i) {
      const float2 w = *reinterpret_cast<const float2*>(&Wo[(size_t)i * DM + c0]);
      const float yv = s_yn[i];
      f0 = fmaf(yv, w.x, f0);
      f1 = fmaf(yv, w.y, f1);
    }
    s_op[kq][2 * l6] = f0; s_op[kq][2 * l6 + 1] = f1;
  }
  __syncthreads();
  if (tid < 128) {
    float a = 0.f;
    #pragma unroll
    for (int kq = 0; kq < 8; ++kq) a += s_op[kq][tid];
    out[(size_t)bp * DM + ct * 128 + tid] = a;
  }
}
}  // namespace

extern "C" void kernel_launch(void* const* d_in, const int* in_sizes, int n_in,
                              void* d_out, int out_size, void* d_ws, size_t ws_size,
                              hipStream_t stream) {
  const float* x    = (const float*)d_in[0];
  const float* t    = (const float*)d_in[1];
  const int*   mask = (const int*)  d_in[2];
  const float* emb  = (const float*)d_in[3];
  const float* Wq   = (const float*)d_in[4];
  const float* Wk   = (const float*)d_in[5];
  const float* Wv   = (const float*)d_in[6];
  const float* Wo   = (const float*)d_in[7];
  const float* lng  = (const float*)d_in[8];
  const float* lnb  = (const float*)d_in[9];
  const float* W1   = (const float*)d_in[10];
  const float* b1   = (const float*)d_in[11];
  const float* W2   = (const float*)d_in[12];
  const float* b2   = (const float*)d_in[13];
  float* out = (float*)d_out;

  float* ws      = (float*)d_ws;
  float* last    = ws;            // 64*256
  float* partial = ws + 16384;    // 16*64*256

  k_attn<<<512, 512, 0, stream>>>(x, t, mask, emb, Wq, Wk, Wv, last);
  k_ffn <<<256, 512, 0, stream>>>(last, W1, b1, W2, partial);
  k_tail<<<256, 512, 0, stream>>>(last, partial, b2, lng, lnb, Wo, out);
}